// Round 4
// baseline (724.550 us; speedup 1.0000x reference)
//
#include <hip/hip_runtime.h>

#define NN      100000
#define NUSERS  50000
#define NE      1250000
#define DIM     64
#define BN_EPS  1e-5f
#define NBLK    391     // ceil(NN / 256)
#define NBUCK   16
#define BCAP    81920   // per-bucket bin capacity (mean 78125, +14 sigma)
#define QCAP    320     // LDS queue depth per bucket (63 residual + 256 insert)

typedef __attribute__((ext_vector_type(8))) short s16x8;
typedef __attribute__((ext_vector_type(4))) float f32x4;

__device__ __forceinline__ short f2b(float f) {  // fp32 -> bf16 RNE
    unsigned u = __builtin_bit_cast(unsigned, f);
    u = (u + 0x7fffu + ((u >> 16) & 1u)) >> 16;
    return (short)u;
}
__device__ __forceinline__ float b2f(unsigned short s) {
    unsigned u = ((unsigned)s) << 16;
    return __builtin_bit_cast(float, u);
}
__device__ __forceinline__ int bucket_of(int d) {  // floor(d/6250), exact for d<100000
    return (int)(((unsigned long long)(unsigned)d * 687195ull) >> 32);
}

// ---------------------------------------------------------------------------
// Single-pass edge binning: read ei ONCE, scatter packed (dst<<32|src) into 16
// per-bucket global bins via LDS queues + 64-wide coalesced flushes.
__global__ __launch_bounds__(256) void bin_edges(const int* __restrict__ ei,
                                                 unsigned long long* __restrict__ bins,
                                                 int* __restrict__ bin_cnt) {
    __shared__ unsigned long long Q[NBUCK][QCAP];
    __shared__ int qn[NBUCK];
    int tid = threadIdx.x;
    int lane = tid & 63, wave = tid >> 6;
    if (tid < NBUCK) qn[tid] = 0;
    __syncthreads();

    int stride = gridDim.x * 256;
    int iters = (NE + stride - 1) / stride;
    int e = blockIdx.x * 256 + tid;
    for (int it = 0; it < iters; ++it, e += stride) {
        if (e < NE) {
            int s = ei[e];
            int d = ei[NE + e];
            int b = bucket_of(d);
            int pos = atomicAdd(&qn[b], 1);
            Q[b][pos] = ((unsigned long long)(unsigned)d << 32) | (unsigned)s;
        }
        __syncthreads();
        // wave w owns buckets 4w..4w+3; flush down to <64
        for (int bb = 0; bb < 4; ++bb) {
            int b = wave * 4 + bb;
            int cnt = qn[b];
            while (cnt >= 64) {
                int base = 0;
                if (lane == 0) base = atomicAdd(&bin_cnt[b], 64);
                base = __shfl(base, 0, 64);
                bins[(size_t)b * BCAP + base + lane] = Q[b][cnt - 64 + lane];
                cnt -= 64;
            }
            if (lane == 0) qn[b] = cnt;
        }
        __syncthreads();
    }
    // tail flush (<64 each)
    for (int bb = 0; bb < 4; ++bb) {
        int b = wave * 4 + bb;
        int cnt = qn[b];
        if (cnt > 0) {
            int base = 0;
            if (lane == 0) base = atomicAdd(&bin_cnt[b], cnt);
            base = __shfl(base, 0, 64);
            if (lane < cnt) bins[(size_t)b * BCAP + base + lane] = Q[b][lane];
        }
    }
}

// ---------------------------------------------------------------------------
// Dense XCD-local degree count over the bins (bucket = blockIdx%16 -> XCD).
__global__ __launch_bounds__(256) void deg_bucket(const unsigned long long* __restrict__ bins,
                                                  const int* __restrict__ bin_cnt,
                                                  int* __restrict__ degi) {
    int b = blockIdx.x & (NBUCK - 1);
    int cnt = bin_cnt[b];
    int i0 = (blockIdx.x >> 4) * 256 + threadIdx.x;
    int stride = (gridDim.x >> 4) * 256;
    for (int i = i0; i < cnt; i += stride) {
        int d = (int)(bins[(size_t)b * BCAP + i] >> 32);
        atomicAdd(&degi[d], 1);
    }
}

// dinv[v] = rsqrt(deg[v] + 1)   (+1 = self-loop)
__global__ __launch_bounds__(256) void dinv_kernel(const int* __restrict__ degi,
                                                   float* __restrict__ dinv) {
    int v = blockIdx.x * blockDim.x + threadIdx.x;
    if (v < NN) dinv[v] = rsqrtf((float)degi[v] + 1.0f);
}

// ---------------------------------------------------------------------------
// Exclusive scan of degi -> row_start (3 passes).
__global__ __launch_bounds__(256) void scan_block_sums(const int* __restrict__ degi,
                                                       int* __restrict__ bsum) {
    __shared__ int ls[256];
    int v = blockIdx.x * 256 + threadIdx.x;
    int d = (v < NN) ? degi[v] : 0;
    ls[threadIdx.x] = d;
    __syncthreads();
    for (int off = 128; off > 0; off >>= 1) {
        if (threadIdx.x < off) ls[threadIdx.x] += ls[threadIdx.x + off];
        __syncthreads();
    }
    if (threadIdx.x == 0) bsum[blockIdx.x] = ls[0];
}

__global__ __launch_bounds__(512) void scan_bsums(const int* __restrict__ bsum,
                                                  int* __restrict__ boff) {
    __shared__ int ls[512];
    int tid = threadIdx.x;
    int val = (tid < NBLK) ? bsum[tid] : 0;
    ls[tid] = val;
    __syncthreads();
    for (int off = 1; off < 512; off <<= 1) {
        int t = (tid >= off) ? ls[tid - off] : 0;
        __syncthreads();
        ls[tid] += t;
        __syncthreads();
    }
    if (tid < NBLK) boff[tid] = ls[tid] - val;  // exclusive
}

__global__ __launch_bounds__(256) void scan_final(const int* __restrict__ degi,
                                                  const int* __restrict__ boff,
                                                  int* __restrict__ row_start,
                                                  int* __restrict__ cursor) {
    __shared__ int ls[256];
    int b = blockIdx.x, tid = threadIdx.x;
    int v = b * 256 + tid;
    int d = (v < NN) ? degi[v] : 0;
    ls[tid] = d;
    __syncthreads();
    for (int off = 1; off < 256; off <<= 1) {
        int t = (tid >= off) ? ls[tid - off] : 0;
        __syncthreads();
        ls[tid] += t;
        __syncthreads();
    }
    int rs = boff[b] + ls[tid] - d;  // exclusive
    if (v < NN) { row_start[v] = rs; cursor[v] = rs; }
    if (b == 0 && tid == 0) row_start[NN] = NE;
}

// ---------------------------------------------------------------------------
// Dense XCD-local CSR placement: csr_src[cursor[dst]++] = src. cursor and the
// bucket's csr region both live in this XCD's L2.
__global__ __launch_bounds__(256) void place_local(const unsigned long long* __restrict__ bins,
                                                   const int* __restrict__ bin_cnt,
                                                   int* __restrict__ cursor,
                                                   int* __restrict__ csr_src) {
    int b = blockIdx.x & (NBUCK - 1);
    int cnt = bin_cnt[b];
    int i0 = (blockIdx.x >> 4) * 256 + threadIdx.x;
    int stride = (gridDim.x >> 4) * 256;
    for (int i = i0; i < cnt; i += stride) {
        unsigned long long p = bins[(size_t)b * BCAP + i];
        int d = (int)(p >> 32);
        int s = (int)(p & 0xffffffffu);
        int pos = atomicAdd(&cursor[d], 1);
        csr_src[pos] = s;
    }
}

// ---------------------------------------------------------------------------
// c0[l][j] = sum_k bs[l][k] * Ws[l+1][j][k]   (bias-fold constants, layers 1,2)
__global__ __launch_bounds__(128) void c0_kernel(const float* __restrict__ Ws,
                                                 const float* __restrict__ bs,
                                                 float* __restrict__ c0) {
    int t = threadIdx.x;
    if (t < 128) {
        int l = t >> 6, j = t & 63;
        const float* Wl = Ws + (size_t)(l + 1) * 4096;
        const float* bl = bs + l * 64;
        float s = 0.0f;
        for (int k = 0; k < 64; ++k) s += bl[k] * Wl[j * 64 + k];
        c0[t] = s;
    }
}

// ---------------------------------------------------------------------------
// bf16 MFMA transform (unchanged from R3): Gb = bf16(scale * (A @ W^T) + dv*c0)
template <int L0>
__global__ __launch_bounds__(256) void gemm_mfma(const void* __restrict__ Xin,
                                                 const float* __restrict__ W,
                                                 const float* __restrict__ dinv,
                                                 const float* __restrict__ c0,
                                                 unsigned short* __restrict__ Gb) {
    int lane = threadIdx.x & 63;
    int n16 = lane & 15, quad = lane >> 4;

    s16x8 bfrag[4][2];
#pragma unroll
    for (int t = 0; t < 4; ++t)
#pragma unroll
        for (int c = 0; c < 2; ++c) {
            const float4* wp = (const float4*)(W + (t * 16 + n16) * 64 + c * 32 + quad * 8);
            float4 w0 = wp[0], w1 = wp[1];
            s16x8 f;
            f[0] = f2b(w0.x); f[1] = f2b(w0.y); f[2] = f2b(w0.z); f[3] = f2b(w0.w);
            f[4] = f2b(w1.x); f[5] = f2b(w1.y); f[6] = f2b(w1.z); f[7] = f2b(w1.w);
            bfrag[t][c] = f;
        }

    int wid = (blockIdx.x * blockDim.x + threadIdx.x) >> 6;
    int nw  = (gridDim.x * blockDim.x) >> 6;
    for (int tile = wid; tile < NN / 16; tile += nw) {
        int r0 = tile * 16;
        int m  = r0 + n16;
        s16x8 a[2];
#pragma unroll
        for (int c = 0; c < 2; ++c) {
            if (L0) {
                const float4* xp = (const float4*)((const float*)Xin + (size_t)m * 64 + c * 32 + quad * 8);
                float4 x0 = xp[0], x1 = xp[1];
                s16x8 f;
                f[0] = f2b(x0.x); f[1] = f2b(x0.y); f[2] = f2b(x0.z); f[3] = f2b(x0.w);
                f[4] = f2b(x1.x); f[5] = f2b(x1.y); f[6] = f2b(x1.z); f[7] = f2b(x1.w);
                a[c] = f;
            } else {
                a[c] = *(const s16x8*)((const unsigned short*)Xin + (size_t)m * 64 + c * 32 + quad * 8);
            }
        }
        f32x4 acc[4] = {{0,0,0,0},{0,0,0,0},{0,0,0,0},{0,0,0,0}};
#pragma unroll
        for (int c = 0; c < 2; ++c)
#pragma unroll
            for (int t = 0; t < 4; ++t)
                acc[t] = __builtin_amdgcn_mfma_f32_16x16x32_bf16(a[c], bfrag[t][c], acc[t], 0, 0, 0);

        float dvr[4];
#pragma unroll
        for (int r = 0; r < 4; ++r) dvr[r] = dinv[r0 + quad * 4 + r];
#pragma unroll
        for (int t = 0; t < 4; ++t) {
            float cc = L0 ? 0.0f : c0[t * 16 + n16];
#pragma unroll
            for (int r = 0; r < 4; ++r) {
                float dv = dvr[r];
                float g  = L0 ? dv * acc[t][r] : dv * dv * acc[t][r] + dv * cc;
                Gb[(size_t)(r0 + quad * 4 + r) * 64 + t * 16 + n16] = (unsigned short)f2b(g);
            }
        }
    }
}

// ---------------------------------------------------------------------------
// Atomic-free gather with 16-deep load batching (mean deg 12.5 -> 1 batch/row).
__global__ __launch_bounds__(256) void gather_b(const int* __restrict__ row_start,
                                                const int* __restrict__ csr_src,
                                                const unsigned short* __restrict__ Gb,
                                                unsigned short* __restrict__ ACCb) {
    int lane = threadIdx.x & 63;
    int wid  = (blockIdx.x * blockDim.x + threadIdx.x) >> 6;
    int nw   = (gridDim.x * blockDim.x) >> 6;
    for (int v = wid; v < NN; v += nw) {
        int rs = row_start[v];
        int re = row_start[v + 1];
        float acc = b2f(Gb[(size_t)v * 64 + lane]);  // self-loop
        for (int base = rs; base < re; base += 64) {
            int n = re - base;
            if (n > 64) n = 64;
            int myidx = (lane < n) ? csr_src[base + lane] : 0;
            for (int t = 0; t < n; t += 16) {
                float tmp[16];
#pragma unroll
                for (int u = 0; u < 16; ++u) {
                    int tt = t + u;
                    int s = __shfl(myidx, (tt < n) ? tt : 0, 64);  // n wave-uniform
                    tmp[u] = b2f(Gb[(size_t)s * 64 + lane]);       // 16 loads in flight
                }
#pragma unroll
                for (int u = 0; u < 16; ++u)
                    acc += (t + u < n) ? tmp[u] : 0.0f;
            }
        }
        ACCb[(size_t)v * 64 + lane] = (unsigned short)f2b(acc);
    }
}

// ---------------------------------------------------------------------------
__global__ __launch_bounds__(256) void bn_stats(const unsigned short* __restrict__ ACCb,
                                                const float* __restrict__ dinv,
                                                const float* __restrict__ blast,
                                                float* __restrict__ sums) {
    int j = threadIdx.x & 63;
    float b = blast[j];
    int wid = (blockIdx.x * blockDim.x + threadIdx.x) >> 6;
    int nw  = (gridDim.x * blockDim.x) >> 6;
    float s = 0.0f, s2 = 0.0f;
    for (int v = wid; v < NN; v += nw) {
        float y = dinv[v] * b2f(ACCb[(size_t)v * 64 + j]) + b;
        s += y;
        s2 += y * y;
    }
    __shared__ float ls[256], ls2[256];
    ls[threadIdx.x] = s;
    ls2[threadIdx.x] = s2;
    __syncthreads();
    if (threadIdx.x < 64) {
        s  = ls[threadIdx.x] + ls[threadIdx.x + 64] + ls[threadIdx.x + 128] + ls[threadIdx.x + 192];
        s2 = ls2[threadIdx.x] + ls2[threadIdx.x + 64] + ls2[threadIdx.x + 128] + ls2[threadIdx.x + 192];
        atomicAdd(&sums[j], s);
        atomicAdd(&sums[64 + j], s2);
    }
}

__global__ __launch_bounds__(256) void bn_apply(const unsigned short* __restrict__ ACCb,
                                                const float* __restrict__ dinv,
                                                const float* __restrict__ blast,
                                                const float* __restrict__ sums,
                                                const float* __restrict__ gamma,
                                                const float* __restrict__ beta,
                                                float* __restrict__ out) {
    const float invN = 1.0f / (float)NN;
    int stride = gridDim.x * blockDim.x;
    for (int i = blockIdx.x * blockDim.x + threadIdx.x; i < NN * 64; i += stride) {
        int j = i & 63;
        int v = i >> 6;
        float mean = sums[j] * invN;
        float var  = sums[64 + j] * invN - mean * mean;
        float y = dinv[v] * b2f(ACCb[i]) + blast[j];
        out[i] = (y - mean) * rsqrtf(var + BN_EPS) * gamma[j] + beta[j];
    }
}

// ---------------------------------------------------------------------------
extern "C" void kernel_launch(void* const* d_in, const int* in_sizes, int n_in,
                              void* d_out, int out_size, void* d_ws, size_t ws_size,
                              hipStream_t stream) {
    const float* x     = (const float*)d_in[0];
    const int*   ei    = (const int*)d_in[1];
    const float* Ws    = (const float*)d_in[2];
    const float* bs    = (const float*)d_in[3];
    const float* gamma = (const float*)d_in[4];
    const float* beta  = (const float*)d_in[5];
    float* out = (float*)d_out;

    char* ws = (char*)d_ws;
    size_t off = 0;
    unsigned long long* bins = (unsigned long long*)(ws + off); off += (size_t)NBUCK * BCAP * 8;
    unsigned short* ACCb = (unsigned short*)(ws + off); off += (size_t)NN * 64 * 2;
    unsigned short* Gb   = (unsigned short*)(ws + off); off += (size_t)NN * 64 * 2;
    float* dinv      = (float*)(ws + off); off += (size_t)NN * 4;
    float* sums      = (float*)(ws + off); off += 128 * 4;
    float* c0        = (float*)(ws + off); off += 128 * 4;
    int*   degi      = (int*)(ws + off);   off += (size_t)NN * 4;
    int*   row_start = (int*)(ws + off);   off += (size_t)(NN + 1) * 4;
    int*   cursor    = (int*)(ws + off);   off += (size_t)NN * 4;
    int*   bsum      = (int*)(ws + off);   off += 512 * 4;
    int*   boff      = (int*)(ws + off);   off += 512 * 4;
    int*   bin_cnt   = (int*)(ws + off);   off += 64 * 4;
    int*   csr_src   = (int*)(ws + off);   off += (size_t)NE * 4;

    hipMemsetAsync(degi, 0, NN * sizeof(int), stream);
    hipMemsetAsync(sums, 0, 128 * sizeof(float), stream);
    hipMemsetAsync(bin_cnt, 0, 64 * sizeof(int), stream);

    // --- CSR build: single-pass bin, then XCD-local dense passes ---
    bin_edges<<<512, 256, 0, stream>>>(ei, bins, bin_cnt);
    deg_bucket<<<512, 256, 0, stream>>>(bins, bin_cnt, degi);
    dinv_kernel<<<(NN + 255) / 256, 256, 0, stream>>>(degi, dinv);
    scan_block_sums<<<NBLK, 256, 0, stream>>>(degi, bsum);
    scan_bsums<<<1, 512, 0, stream>>>(bsum, boff);
    scan_final<<<NBLK, 256, 0, stream>>>(degi, boff, row_start, cursor);
    place_local<<<512, 256, 0, stream>>>(bins, bin_cnt, cursor, csr_src);
    c0_kernel<<<1, 128, 0, stream>>>(Ws, bs, c0);

    // --- 3 GCN layers ---
    gemm_mfma<1><<<1563, 256, 0, stream>>>(x, Ws, dinv, nullptr, Gb);
    gather_b<<<2048, 256, 0, stream>>>(row_start, csr_src, Gb, ACCb);
    for (int l = 1; l < 3; ++l) {
        gemm_mfma<0><<<1563, 256, 0, stream>>>(ACCb, Ws + (size_t)l * 4096, dinv,
                                               c0 + (l - 1) * 64, Gb);
        gather_b<<<2048, 256, 0, stream>>>(row_start, csr_src, Gb, ACCb);
    }

    // --- BatchNorm over nodes ---
    bn_stats<<<2048, 256, 0, stream>>>(ACCb, dinv, bs + 128, sums);
    bn_apply<<<2048, 256, 0, stream>>>(ACCb, dinv, bs + 128, sums, gamma, beta, out);
}

// Round 5
// 469.712 us; speedup vs baseline: 1.5425x; 1.5425x over previous
//
#include <hip/hip_runtime.h>

#define NN      100000
#define NUSERS  50000
#define NE      1250000
#define DIM     64
#define BN_EPS  1e-5f
#define NBLK    391     // ceil(NN / 256)
#define NBUCK   16
#define NCHUNK  160     // blocks per bucket (grid 2560 -> full occupancy)

typedef __attribute__((ext_vector_type(8))) short s16x8;
typedef __attribute__((ext_vector_type(4))) float f32x4;

__device__ __forceinline__ short f2b(float f) {  // fp32 -> bf16 RNE
    unsigned u = __builtin_bit_cast(unsigned, f);
    u = (u + 0x7fffu + ((u >> 16) & 1u)) >> 16;
    return (short)u;
}
__device__ __forceinline__ float b2f(unsigned short s) {
    unsigned u = ((unsigned)s) << 16;
    return __builtin_bit_cast(float, u);
}
__device__ __forceinline__ int bucket_of(int d) {  // floor(d/6250), exact for d<100000
    return (int)(((unsigned long long)(unsigned)d * 687195ull) >> 32);
}

// ---------------------------------------------------------------------------
// Partitioned degree count: block handles bucket blockIdx%16 (XCD-local lines),
// wave-private LDS queue densifies the 1/16-sparse kept lanes.
// nt loads keep the 16x ei stream from evicting atomic/write lines in L2.
__global__ __launch_bounds__(256) void deg_part(const int* __restrict__ ei,
                                                int* __restrict__ degi) {
    __shared__ int Qd[4][128];
    int lane = threadIdx.x & 63, wave = threadIdx.x >> 6;
    int B = blockIdx.x & (NBUCK - 1);
    int gw = (blockIdx.x >> 4) * 4 + wave;           // wave id within bucket
    const int NW  = NCHUNK * 4;
    const int per = (NE + NW - 1) / NW;
    int e0 = gw * per;
    int e1 = e0 + per; if (e1 > NE) e1 = NE;
    int qn = 0;
    for (int e = e0 + lane; e - lane < e1; e += 64) {
        bool keep = false; int d = 0;
        if (e < e1) { d = __builtin_nontemporal_load(&ei[NE + e]); keep = (bucket_of(d) == B); }
        unsigned long long m = __ballot(keep);
        if (keep) {
            int rank = __popcll(m & ((1ull << lane) - 1ull));
            Qd[wave][qn + rank] = d;
        }
        qn += __popcll(m);
        if (qn >= 64) {
            int dd = Qd[wave][lane];
            atomicAdd(&degi[dd], 1);
            qn -= 64;
            int mv = (lane < qn) ? Qd[wave][64 + lane] : 0;
            if (lane < qn) Qd[wave][lane] = mv;
        }
    }
    if (lane < qn) atomicAdd(&degi[Qd[wave][lane]], 1);
}

// ---------------------------------------------------------------------------
// Exclusive scan of degi -> row_start (3 passes); dinv folded into pass 3.
__global__ __launch_bounds__(256) void scan_block_sums(const int* __restrict__ degi,
                                                       int* __restrict__ bsum) {
    __shared__ int ls[256];
    int v = blockIdx.x * 256 + threadIdx.x;
    int d = (v < NN) ? degi[v] : 0;
    ls[threadIdx.x] = d;
    __syncthreads();
    for (int off = 128; off > 0; off >>= 1) {
        if (threadIdx.x < off) ls[threadIdx.x] += ls[threadIdx.x + off];
        __syncthreads();
    }
    if (threadIdx.x == 0) bsum[blockIdx.x] = ls[0];
}

__global__ __launch_bounds__(512) void scan_bsums(const int* __restrict__ bsum,
                                                  int* __restrict__ boff) {
    __shared__ int ls[512];
    int tid = threadIdx.x;
    int val = (tid < NBLK) ? bsum[tid] : 0;
    ls[tid] = val;
    __syncthreads();
    for (int off = 1; off < 512; off <<= 1) {
        int t = (tid >= off) ? ls[tid - off] : 0;
        __syncthreads();
        ls[tid] += t;
        __syncthreads();
    }
    if (tid < NBLK) boff[tid] = ls[tid] - val;  // exclusive
}

__global__ __launch_bounds__(256) void scan_final(const int* __restrict__ degi,
                                                  const int* __restrict__ boff,
                                                  int* __restrict__ row_start,
                                                  int* __restrict__ cursor,
                                                  float* __restrict__ dinv) {
    __shared__ int ls[256];
    int b = blockIdx.x, tid = threadIdx.x;
    int v = b * 256 + tid;
    int d = (v < NN) ? degi[v] : 0;
    ls[tid] = d;
    __syncthreads();
    for (int off = 1; off < 256; off <<= 1) {
        int t = (tid >= off) ? ls[tid - off] : 0;
        __syncthreads();
        ls[tid] += t;
        __syncthreads();
    }
    int rs = boff[b] + ls[tid] - d;  // exclusive
    if (v < NN) {
        row_start[v] = rs;
        cursor[v]    = rs;
        dinv[v]      = rsqrtf((float)d + 1.0f);
    }
    if (b == 0 && tid == 0) row_start[NN] = NE;
}

// ---------------------------------------------------------------------------
// Partitioned placement with wave queue: csr_src[cursor[dst]++] = src.
__global__ __launch_bounds__(256) void place_part(const int* __restrict__ ei,
                                                  int* __restrict__ cursor,
                                                  int* __restrict__ csr_src) {
    __shared__ int Qd[4][128];
    __shared__ int Qs[4][128];
    int lane = threadIdx.x & 63, wave = threadIdx.x >> 6;
    int B = blockIdx.x & (NBUCK - 1);
    int gw = (blockIdx.x >> 4) * 4 + wave;
    const int NW  = NCHUNK * 4;
    const int per = (NE + NW - 1) / NW;
    int e0 = gw * per;
    int e1 = e0 + per; if (e1 > NE) e1 = NE;
    int qn = 0;
    for (int e = e0 + lane; e - lane < e1; e += 64) {
        bool keep = false; int d = 0, s = 0;
        if (e < e1) {
            d = __builtin_nontemporal_load(&ei[NE + e]);
            keep = (bucket_of(d) == B);
            if (keep) s = __builtin_nontemporal_load(&ei[e]);
        }
        unsigned long long m = __ballot(keep);
        if (keep) {
            int rank = __popcll(m & ((1ull << lane) - 1ull));
            Qd[wave][qn + rank] = d;
            Qs[wave][qn + rank] = s;
        }
        qn += __popcll(m);
        if (qn >= 64) {
            int dd = Qd[wave][lane];
            int ss = Qs[wave][lane];
            int pos = atomicAdd(&cursor[dd], 1);
            csr_src[pos] = ss;
            qn -= 64;
            int mvd = (lane < qn) ? Qd[wave][64 + lane] : 0;
            int mvs = (lane < qn) ? Qs[wave][64 + lane] : 0;
            if (lane < qn) { Qd[wave][lane] = mvd; Qs[wave][lane] = mvs; }
        }
    }
    if (lane < qn) {
        int pos = atomicAdd(&cursor[Qd[wave][lane]], 1);
        csr_src[pos] = Qs[wave][lane];
    }
}

// ---------------------------------------------------------------------------
// c0[l][j] = sum_k bs[l][k] * Ws[l+1][j][k]   (bias-fold constants, layers 1,2)
__global__ __launch_bounds__(128) void c0_kernel(const float* __restrict__ Ws,
                                                 const float* __restrict__ bs,
                                                 float* __restrict__ c0) {
    int t = threadIdx.x;
    if (t < 128) {
        int l = t >> 6, j = t & 63;
        const float* Wl = Ws + (size_t)(l + 1) * 4096;
        const float* bl = bs + l * 64;
        float s = 0.0f;
        for (int k = 0; k < 64; ++k) s += bl[k] * Wl[j * 64 + k];
        c0[t] = s;
    }
}

// ---------------------------------------------------------------------------
// bf16 MFMA transform: Gb = bf16(scale * (A @ W^T) + dv*c0)
template <int L0>
__global__ __launch_bounds__(256) void gemm_mfma(const void* __restrict__ Xin,
                                                 const float* __restrict__ W,
                                                 const float* __restrict__ dinv,
                                                 const float* __restrict__ c0,
                                                 unsigned short* __restrict__ Gb) {
    int lane = threadIdx.x & 63;
    int n16 = lane & 15, quad = lane >> 4;

    s16x8 bfrag[4][2];
#pragma unroll
    for (int t = 0; t < 4; ++t)
#pragma unroll
        for (int c = 0; c < 2; ++c) {
            const float4* wp = (const float4*)(W + (t * 16 + n16) * 64 + c * 32 + quad * 8);
            float4 w0 = wp[0], w1 = wp[1];
            s16x8 f;
            f[0] = f2b(w0.x); f[1] = f2b(w0.y); f[2] = f2b(w0.z); f[3] = f2b(w0.w);
            f[4] = f2b(w1.x); f[5] = f2b(w1.y); f[6] = f2b(w1.z); f[7] = f2b(w1.w);
            bfrag[t][c] = f;
        }

    int wid = (blockIdx.x * blockDim.x + threadIdx.x) >> 6;
    int nw  = (gridDim.x * blockDim.x) >> 6;
    for (int tile = wid; tile < NN / 16; tile += nw) {
        int r0 = tile * 16;
        int m  = r0 + n16;
        s16x8 a[2];
#pragma unroll
        for (int c = 0; c < 2; ++c) {
            if (L0) {
                const float4* xp = (const float4*)((const float*)Xin + (size_t)m * 64 + c * 32 + quad * 8);
                float4 x0 = xp[0], x1 = xp[1];
                s16x8 f;
                f[0] = f2b(x0.x); f[1] = f2b(x0.y); f[2] = f2b(x0.z); f[3] = f2b(x0.w);
                f[4] = f2b(x1.x); f[5] = f2b(x1.y); f[6] = f2b(x1.z); f[7] = f2b(x1.w);
                a[c] = f;
            } else {
                a[c] = *(const s16x8*)((const unsigned short*)Xin + (size_t)m * 64 + c * 32 + quad * 8);
            }
        }
        f32x4 acc[4] = {{0,0,0,0},{0,0,0,0},{0,0,0,0},{0,0,0,0}};
#pragma unroll
        for (int c = 0; c < 2; ++c)
#pragma unroll
            for (int t = 0; t < 4; ++t)
                acc[t] = __builtin_amdgcn_mfma_f32_16x16x32_bf16(a[c], bfrag[t][c], acc[t], 0, 0, 0);

        float dvr[4];
#pragma unroll
        for (int r = 0; r < 4; ++r) dvr[r] = dinv[r0 + quad * 4 + r];
#pragma unroll
        for (int t = 0; t < 4; ++t) {
            float cc = L0 ? 0.0f : c0[t * 16 + n16];
#pragma unroll
            for (int r = 0; r < 4; ++r) {
                float dv = dvr[r];
                float g  = L0 ? dv * acc[t][r] : dv * dv * acc[t][r] + dv * cc;
                Gb[(size_t)(r0 + quad * 4 + r) * 64 + t * 16 + n16] = (unsigned short)f2b(g);
            }
        }
    }
}

// ---------------------------------------------------------------------------
// Gather, 4 neighbors per wave-instruction: lane = 16*g + c; group g loads the
// 8B chunk (cols 4c..4c+3) of neighbor 4b+g. One load instr = 4 full rows.
// Cross-group shfl_xor(16,32) combines the 4 partial sums.
__global__ __launch_bounds__(256) void gather_b(const int* __restrict__ row_start,
                                                const int* __restrict__ csr_src,
                                                const unsigned short* __restrict__ Gb,
                                                unsigned short* __restrict__ ACCb) {
    int lane = threadIdx.x & 63;
    int c = lane & 15, g = lane >> 4;
    int wid  = (blockIdx.x * blockDim.x + threadIdx.x) >> 6;
    int nw   = (gridDim.x * blockDim.x) >> 6;
    for (int v = wid; v < NN; v += nw) {
        int rs = row_start[v];
        int re = row_start[v + 1];
        // self-loop: group 0 only
        float ax = 0.f, ay = 0.f, az = 0.f, aw = 0.f;
        {
            ushort4 sv = *(const ushort4*)(Gb + (size_t)v * 64 + c * 4);
            float m0 = (g == 0) ? 1.0f : 0.0f;
            ax = m0 * b2f(sv.x); ay = m0 * b2f(sv.y);
            az = m0 * b2f(sv.z); aw = m0 * b2f(sv.w);
        }
        for (int base = rs; base < re; base += 64) {
            int n = re - base;
            if (n > 64) n = 64;
            int myidx = (lane < n) ? csr_src[base + lane] : 0;
            for (int t = 0; t < n; t += 16) {
                ushort4 val[4];
                float msk[4];
#pragma unroll
                for (int u = 0; u < 4; ++u) {
                    int nb = t + u * 4 + g;              // neighbor slot in window
                    int s = __shfl(myidx, nb & 63, 64);
                    bool ok = nb < n;
                    msk[u] = ok ? 1.0f : 0.0f;
                    const ushort4* p = (const ushort4*)(Gb + (size_t)(ok ? s : v) * 64 + c * 4);
                    val[u] = *p;                          // 4 independent loads in flight
                }
#pragma unroll
                for (int u = 0; u < 4; ++u) {
                    ax = fmaf(msk[u], b2f(val[u].x), ax);
                    ay = fmaf(msk[u], b2f(val[u].y), ay);
                    az = fmaf(msk[u], b2f(val[u].z), az);
                    aw = fmaf(msk[u], b2f(val[u].w), aw);
                }
            }
        }
        // combine the 4 group partials: every lane ends with the full sum
#pragma unroll
        for (int off = 16; off < 64; off <<= 1) {
            ax += __shfl_xor(ax, off, 64);
            ay += __shfl_xor(ay, off, 64);
            az += __shfl_xor(az, off, 64);
            aw += __shfl_xor(aw, off, 64);
        }
        if (g == 0) {
            ushort4 o;
            o.x = (unsigned short)f2b(ax); o.y = (unsigned short)f2b(ay);
            o.z = (unsigned short)f2b(az); o.w = (unsigned short)f2b(aw);
            *(ushort4*)(ACCb + (size_t)v * 64 + c * 4) = o;
        }
    }
}

// ---------------------------------------------------------------------------
__global__ __launch_bounds__(256) void bn_stats(const unsigned short* __restrict__ ACCb,
                                                const float* __restrict__ dinv,
                                                const float* __restrict__ blast,
                                                float* __restrict__ sums) {
    int j = threadIdx.x & 63;
    float b = blast[j];
    int wid = (blockIdx.x * blockDim.x + threadIdx.x) >> 6;
    int nw  = (gridDim.x * blockDim.x) >> 6;
    float s = 0.0f, s2 = 0.0f;
    for (int v = wid; v < NN; v += nw) {
        float y = dinv[v] * b2f(ACCb[(size_t)v * 64 + j]) + b;
        s += y;
        s2 += y * y;
    }
    __shared__ float ls[256], ls2[256];
    ls[threadIdx.x] = s;
    ls2[threadIdx.x] = s2;
    __syncthreads();
    if (threadIdx.x < 64) {
        s  = ls[threadIdx.x] + ls[threadIdx.x + 64] + ls[threadIdx.x + 128] + ls[threadIdx.x + 192];
        s2 = ls2[threadIdx.x] + ls2[threadIdx.x + 64] + ls2[threadIdx.x + 128] + ls2[threadIdx.x + 192];
        atomicAdd(&sums[j], s);
        atomicAdd(&sums[64 + j], s2);
    }
}

__global__ __launch_bounds__(256) void bn_apply(const unsigned short* __restrict__ ACCb,
                                                const float* __restrict__ dinv,
                                                const float* __restrict__ blast,
                                                const float* __restrict__ sums,
                                                const float* __restrict__ gamma,
                                                const float* __restrict__ beta,
                                                float* __restrict__ out) {
    const float invN = 1.0f / (float)NN;
    int stride = gridDim.x * blockDim.x;
    for (int i = blockIdx.x * blockDim.x + threadIdx.x; i < NN * 64; i += stride) {
        int j = i & 63;
        int v = i >> 6;
        float mean = sums[j] * invN;
        float var  = sums[64 + j] * invN - mean * mean;
        float y = dinv[v] * b2f(ACCb[i]) + blast[j];
        out[i] = (y - mean) * rsqrtf(var + BN_EPS) * gamma[j] + beta[j];
    }
}

// ---------------------------------------------------------------------------
extern "C" void kernel_launch(void* const* d_in, const int* in_sizes, int n_in,
                              void* d_out, int out_size, void* d_ws, size_t ws_size,
                              hipStream_t stream) {
    const float* x     = (const float*)d_in[0];
    const int*   ei    = (const int*)d_in[1];
    const float* Ws    = (const float*)d_in[2];
    const float* bs    = (const float*)d_in[3];
    const float* gamma = (const float*)d_in[4];
    const float* beta  = (const float*)d_in[5];
    float* out = (float*)d_out;

    char* ws = (char*)d_ws;
    size_t off = 0;
    unsigned short* ACCb = (unsigned short*)(ws + off); off += (size_t)NN * 64 * 2;
    unsigned short* Gb   = (unsigned short*)(ws + off); off += (size_t)NN * 64 * 2;
    float* dinv      = (float*)(ws + off); off += (size_t)NN * 4;
    float* sums      = (float*)(ws + off); off += 128 * 4;
    float* c0        = (float*)(ws + off); off += 128 * 4;
    int*   degi      = (int*)(ws + off);   off += (size_t)NN * 4;
    int*   row_start = (int*)(ws + off);   off += (size_t)(NN + 1) * 4;
    int*   cursor    = (int*)(ws + off);   off += (size_t)NN * 4;
    int*   bsum      = (int*)(ws + off);   off += 512 * 4;
    int*   boff      = (int*)(ws + off);   off += 512 * 4;
    int*   csr_src   = (int*)(ws + off);   off += (size_t)NE * 4;

    hipMemsetAsync(degi, 0, NN * sizeof(int), stream);
    hipMemsetAsync(sums, 0, 128 * sizeof(float), stream);

    // --- CSR build (XCD-partitioned, full occupancy) ---
    deg_part<<<NBUCK * NCHUNK, 256, 0, stream>>>(ei, degi);
    scan_block_sums<<<NBLK, 256, 0, stream>>>(degi, bsum);
    scan_bsums<<<1, 512, 0, stream>>>(bsum, boff);
    scan_final<<<NBLK, 256, 0, stream>>>(degi, boff, row_start, cursor, dinv);
    place_part<<<NBUCK * NCHUNK, 256, 0, stream>>>(ei, cursor, csr_src);
    c0_kernel<<<1, 128, 0, stream>>>(Ws, bs, c0);

    // --- 3 GCN layers ---
    gemm_mfma<1><<<1563, 256, 0, stream>>>(x, Ws, dinv, nullptr, Gb);
    gather_b<<<2048, 256, 0, stream>>>(row_start, csr_src, Gb, ACCb);
    for (int l = 1; l < 3; ++l) {
        gemm_mfma<0><<<1563, 256, 0, stream>>>(ACCb, Ws + (size_t)l * 4096, dinv,
                                               c0 + (l - 1) * 64, Gb);
        gather_b<<<2048, 256, 0, stream>>>(row_start, csr_src, Gb, ACCb);
    }

    // --- BatchNorm over nodes ---
    bn_stats<<<2048, 256, 0, stream>>>(ACCb, dinv, bs + 128, sums);
    bn_apply<<<2048, 256, 0, stream>>>(ACCb, dinv, bs + 128, sums, gamma, beta, out);
}